// Round 12
// baseline (3315.202 us; speedup 1.0000x reference)
//
#include <hip/hip_runtime.h>
#include <hip/hip_bf16.h>
#include <cstdint>

#define EPS 1e-5

typedef __attribute__((ext_vector_type(4))) int int32x4;

// =============================================================================
// numpy-exact fp32 pairwise mean of |w| (see round 2-4 notes). Fused: all three
// weight matrices in one kernel per tree level.
// =============================================================================
__device__ inline float np_leaf_abs(const float* __restrict__ a, int n) {
  float r[8];
  #pragma unroll
  for (int j = 0; j < 8; j++) r[j] = fabsf(a[j]);
  for (int i = 8; i < n; i += 8) {
    #pragma unroll
    for (int j = 0; j < 8; j++) r[j] += fabsf(a[i + j]);
  }
  return ((r[0] + r[1]) + (r[2] + r[3])) + ((r[4] + r[5]) + (r[6] + r[7]));
}

__global__ __launch_bounds__(256) void np_blocksums3(
    const float* __restrict__ w0, const float* __restrict__ w1,
    const float* __restrict__ w2, float* __restrict__ bs) {
  int b = blockIdx.x * 256 + threadIdx.x;       // [0, 393216)
  const float* w = (b < 131072) ? w0 : (b < 262144 ? w1 : w2);
  long lb = b & 131071;
  const float* a = w + lb * 344;
  float s0 = np_leaf_abs(a, 80);
  float s1 = np_leaf_abs(a + 80, 88);
  float s2 = np_leaf_abs(a + 168, 88);
  float s3 = np_leaf_abs(a + 256, 88);
  bs[b] = (s0 + s1) + (s2 + s3);
}

__global__ __launch_bounds__(256) void np_tree_partial3(
    const float* __restrict__ bs, float* __restrict__ part) {
  __shared__ float sh[256];
  int t = threadIdx.x;
  const float* a = bs + (long)blockIdx.x * 512;   // grid 768 = 3*256
  sh[t] = a[2 * t] + a[2 * t + 1];
  __syncthreads();
  for (int n = 128; n >= 1; n >>= 1) {
    float x = 0.f;
    if (t < n) x = sh[2 * t] + sh[2 * t + 1];
    __syncthreads();
    if (t < n) sh[t] = x;
    __syncthreads();
  }
  if (t == 0) part[blockIdx.x] = sh[0];
}

__global__ __launch_bounds__(128) void np_tree_final3(
    const float* __restrict__ part, float* __restrict__ meanw) {
  __shared__ float sh[128];
  int t = threadIdx.x;
  const float* p = part + blockIdx.x * 256;     // grid 3
  sh[t] = p[2 * t] + p[2 * t + 1];
  __syncthreads();
  for (int n = 64; n >= 1; n >>= 1) {
    float x = 0.f;
    if (t < n) x = sh[2 * t] + sh[2 * t + 1];
    __syncthreads();
    if (t < n) sh[t] = x;
    __syncthreads();
  }
  if (t == 0) meanw[blockIdx.x] = sh[0] / 45088768.0f;
}

// ------------------------------------------------------- weight ternarize
__global__ __launch_bounds__(256) void quant_w_gu(
    const float* __restrict__ wg, const float* __restrict__ wu,
    const float* __restrict__ meanw, char* __restrict__ qg, char* __restrict__ qu,
    long n4) {
  int half = (blockIdx.x >= 4096);
  const float* w = half ? wu : wg;
  char* q = half ? qu : qg;
  float scale = 1.0f / fmaxf(meanw[half], 1e-5f);
  long i = (long)(blockIdx.x & 4095) * blockDim.x + threadIdx.x;
  long stride = 4096L * blockDim.x;
  const float4* w4 = (const float4*)w;
  char4* q4 = (char4*)q;
  for (; i < n4; i += stride) {
    float4 v = w4[i];
    char4 c;
    c.x = (char)(int)fminf(1.f, fmaxf(-1.f, rintf(v.x * scale)));
    c.y = (char)(int)fminf(1.f, fmaxf(-1.f, rintf(v.y * scale)));
    c.z = (char)(int)fminf(1.f, fmaxf(-1.f, rintf(v.z * scale)));
    c.w = (char)(int)fminf(1.f, fmaxf(-1.f, rintf(v.w * scale)));
    q4[i] = c;
  }
}

#define CORR_MAX 1024
#define WIN 1e-6f

__global__ __launch_bounds__(256) void quant_w_down(
    const float* __restrict__ w, const float* __restrict__ mean_ptr,
    char* __restrict__ q, int* __restrict__ cnt,
    int* __restrict__ ck, float* __restrict__ cv) {
  float scale = 1.0f / fmaxf(mean_ptr[2], 1e-5f);
  long i0 = ((long)blockIdx.x * blockDim.x + threadIdx.x) * 4;
  long stride = (long)gridDim.x * blockDim.x * 4;
  for (long i = i0; i < 4096L * 11008L; i += stride) {
    char4 c;
    #pragma unroll
    for (int j = 0; j < 4; j++) {
      float t = w[i + j] * scale;
      float qv = fminf(1.f, fmaxf(-1.f, rintf(t)));
      if (fabsf(fabsf(t) - 0.5f) < WIN) {
        qv = 0.f;
        int idx = atomicAdd(cnt, 1);
        if (idx < CORR_MAX) {
          ck[idx] = (int)(i + j);                 // flat n*11008+k
          cv[idx] = t > 0.f ? 0.5f : -0.5f;
        }
      }
      ((char*)&c)[j] = (char)(int)qv;
    }
    *(char4*)(q + i) = c;
  }
}

__global__ void zero_cnt(int* cnt) { *cnt = 0; }

__global__ __launch_bounds__(64) void apply_corr(
    const int* __restrict__ cnt, const int* __restrict__ ck,
    const float* __restrict__ cv, const char* __restrict__ qh,
    const float* __restrict__ fh, const float* __restrict__ meanw,
    float* __restrict__ out) {
  int r = blockIdx.x * 64 + threadIdx.x;  // 8192 rows
  float fwd = fmaxf(meanw[2], 1e-5f);
  int n = *cnt; if (n > CORR_MAX) n = CORR_MAX;
  float fr = fh[r] * fwd;
  for (int i = 0; i < n; i++) {
    int flat = ck[i];
    int nn = flat / 11008, kk = flat % 11008;
    float qv = (float)qh[(long)r * 11008 + kk];
    out[(long)r * 4096 + nn] += cv[i] * qv * fr;
  }
}

// ---------------------------------------------------------------- reductions
__device__ inline void block_reduce_sum_max_d(double& s, float& m) {
  #pragma unroll
  for (int off = 1; off < 64; off <<= 1) {
    s += __shfl_xor(s, off, 64);
    m = fmaxf(m, __shfl_xor(m, off, 64));
  }
  __shared__ double ssh[4];
  __shared__ float msh[4];
  int wv = threadIdx.x >> 6;
  if ((threadIdx.x & 63) == 0) { ssh[wv] = s; msh[wv] = m; }
  __syncthreads();
  s = (ssh[0] + ssh[1]) + (ssh[2] + ssh[3]);
  m = fmaxf(fmaxf(msh[0], msh[1]), fmaxf(msh[2], msh[3]));
}

// ------------------------------------------------------- activation quant
__device__ inline char quant1d(float x, double rn, double s) {
  double t = (double)x * rn;
  double q = rint(t * s);
  q = fmin(127.0, fmax(-128.0, q));
  return (char)(int)q;
}

__global__ __launch_bounds__(256) void act_quant_x(
    const float* __restrict__ x, char* __restrict__ qx, float* __restrict__ fx) {
  const int row = blockIdx.x;
  const float4* xr = (const float4*)(x + (long)row * 4096);
  float4 v[4];
  double ss = 0.0;
  float am = 0.f;
  #pragma unroll
  for (int i = 0; i < 4; i++) {
    v[i] = xr[i * 256 + threadIdx.x];
    ss += ((double)v[i].x * v[i].x + (double)v[i].y * v[i].y) +
          ((double)v[i].z * v[i].z + (double)v[i].w * v[i].w);
    am = fmaxf(am, fmaxf(fmaxf(fabsf(v[i].x), fabsf(v[i].y)),
                         fmaxf(fabsf(v[i].z), fabsf(v[i].w))));
  }
  block_reduce_sum_max_d(ss, am);
  double rn = 1.0 / sqrt(ss / 4096.0 + EPS);
  double den = fmax((double)am * rn, EPS);
  double s = 127.0 / den;
  if (threadIdx.x == 0) fx[row] = (float)(den / 127.0);
  char4* qr = (char4*)(qx + (long)row * 4096);
  #pragma unroll
  for (int i = 0; i < 4; i++) {
    char4 c;
    c.x = quant1d(v[i].x, rn, s);
    c.y = quant1d(v[i].y, rn, s);
    c.z = quant1d(v[i].z, rn, s);
    c.w = quant1d(v[i].w, rn, s);
    qr[i * 256 + threadIdx.x] = c;
  }
}

// h row cached in LDS (44KB) so the quant pass doesn't re-read 360MB from HBM.
__global__ __launch_bounds__(256) void act_quant_h(
    const float* __restrict__ h, char* __restrict__ qh, float* __restrict__ fh) {
  __shared__ float4 hrow4[2752];
  const long row = blockIdx.x;
  const float4* hr = (const float4*)(h + row * 11008);
  double ss = 0.0;
  float am = 0.f;
  for (int i = threadIdx.x; i < 2752; i += 256) {
    float4 v = hr[i];
    hrow4[i] = v;
    ss += ((double)v.x * v.x + (double)v.y * v.y) +
          ((double)v.z * v.z + (double)v.w * v.w);
    am = fmaxf(am, fmaxf(fmaxf(fabsf(v.x), fabsf(v.y)),
                         fmaxf(fabsf(v.z), fabsf(v.w))));
  }
  block_reduce_sum_max_d(ss, am);   // contains __syncthreads (covers hrow4)
  double rn = 1.0 / sqrt(ss / 11008.0 + EPS);
  double den = fmax((double)am * rn, EPS);
  double s = 127.0 / den;
  if (threadIdx.x == 0) fh[row] = (float)(den / 127.0);
  char4* qr = (char4*)(qh + row * 11008);
  for (int i = threadIdx.x; i < 2752; i += 256) {
    float4 v = hrow4[i];
    char4 c;
    c.x = quant1d(v.x, rn, s);
    c.y = quant1d(v.y, rn, s);
    c.z = quant1d(v.z, rn, s);
    c.w = quant1d(v.w, rn, s);
    qr[i] = c;
  }
}

// =============================================================================
// GEMMs: AITER-flatmm style — NO LDS, NO BARRIERS. Each wave loads its MFMA
// fragments DIRECTLY global->register (B panels are L2-resident under the
// m-fastest XCD grid; A is L3-resident) and free-runs {load-next ; MFMA-cur}
// with register double-buffering. A wave's frag load = 16 rows x 64B
// contiguous segments (4 lanes per segment) — L2-friendly. The MFMA pipe
// serializes the 2 waves/SIMD back-to-back; load latency hides under the
// ~650-cyc MFMA cluster. Counted vmcnt inserted by the compiler via the
// named-register dependency chains (no inline-asm reads -> tracking is exact).
//   gateup: 128x128 tile, 4 waves (2x2 of 64x64 per matrix).
//   down:   128x256 tile, 4 waves (2m x 2n of 64x128).
// Fragment addressing = the logical layout validated since r4:
//   row = wtile + frag*16 + (lane&15), col = (lane>>4)*16 (+k0).
// =============================================================================

__global__ __launch_bounds__(256, 2) void gemm_gateup(
    const char* __restrict__ qx, const char* __restrict__ qwg, const char* __restrict__ qwu,
    const float* __restrict__ meanw, const float* __restrict__ fx, float* __restrict__ h) {
  const int t = threadIdx.x;
  const int lane = t & 63;
  const int wv = t >> 6;                       // 0..3
  const int bid = blockIdx.x;                  // 5504 = 8 * 688
  const int swz = (bid & 7) * 688 + (bid >> 3);
  const int m0 = (swz & 63) * 128;
  const int n0 = (swz >> 6) * 128;
  const int wm = (wv >> 1) * 64;
  const int wn = (wv & 1) * 64;

  const int r15 = lane & 15;
  const int kb = (lane >> 4) * 16;

  const char* pA = qx  + (long)(m0 + wm + r15) * 4096 + kb;
  const char* pG = qwg + (long)(n0 + wn + r15) * 4096 + kb;
  const char* pU = qwu + (long)(n0 + wn + r15) * 4096 + kb;
  const long RS = 16L * 4096;

  int32x4 accg[4][4] = {};
  int32x4 accu[4][4] = {};
  int32x4 a0[4], g0[4], u0[4], a1[4], g1[4], u1[4];

  #define GU_LOAD(ar, gr, ur, k0)                              \
    do {                                                       \
      _Pragma("unroll")                                        \
      for (int m = 0; m < 4; m++)                              \
        ar[m] = *(const int32x4*)(pA + m * RS + (k0));         \
      _Pragma("unroll")                                        \
      for (int n = 0; n < 4; n++) {                            \
        gr[n] = *(const int32x4*)(pG + n * RS + (k0));         \
        ur[n] = *(const int32x4*)(pU + n * RS + (k0));         \
      }                                                        \
    } while (0)

  #define GU_MFMA(ar, gr, ur)                                                \
    do {                                                                     \
      __builtin_amdgcn_s_setprio(1);                                         \
      _Pragma("unroll")                                                      \
      for (int n = 0; n < 4; n++) {                                          \
        _Pragma("unroll")                                                    \
        for (int m = 0; m < 4; m++) {                                        \
          accg[m][n] = __builtin_amdgcn_mfma_i32_16x16x64_i8(ar[m], gr[n], accg[m][n], 0, 0, 0); \
          accu[m][n] = __builtin_amdgcn_mfma_i32_16x16x64_i8(ar[m], ur[n], accu[m][n], 0, 0, 0); \
        }                                                                    \
      }                                                                      \
      __builtin_amdgcn_s_setprio(0);                                         \
    } while (0)

  GU_LOAD(a0, g0, u0, 0);
  for (int ks = 0; ks < 64; ks += 2) {
    if (ks + 1 < 64) GU_LOAD(a1, g1, u1, (ks + 1) * 64);
    GU_MFMA(a0, g0, u0);
    if (ks + 2 < 64) GU_LOAD(a0, g0, u0, (ks + 2) * 64);
    GU_MFMA(a1, g1, u1);
  }
  #undef GU_LOAD
  #undef GU_MFMA

  float fwg = fmaxf(meanw[0], 1e-5f);
  float fwu = fmaxf(meanw[1], 1e-5f);
  const int rgrp = lane >> 4;
  const int cidx = lane & 15;
  #pragma unroll
  for (int m = 0; m < 4; m++) {
    #pragma unroll
    for (int r = 0; r < 4; r++) {
      int grow = m0 + wm + m * 16 + rgrp * 4 + r;
      float fxr = fx[grow];
      float sg = fxr * fwg, su = fxr * fwu;
      #pragma unroll
      for (int n = 0; n < 4; n++) {
        float g = (float)accg[m][n][r] * sg;
        float u = (float)accu[m][n][r] * su;
        float hv = g / (1.f + expf(-g)) * u;
        h[(long)grow * 11008 + (n0 + wn + n * 16 + cidx)] = hv;
      }
    }
  }
}

__global__ __launch_bounds__(256, 2) void gemm_down(
    const char* __restrict__ qh, const char* __restrict__ qwd,
    const float* __restrict__ meanw, const float* __restrict__ fh,
    float* __restrict__ out) {
  const int t = threadIdx.x;
  const int lane = t & 63;
  const int wv = t >> 6;
  const int bid = blockIdx.x;                  // 1024 = 8 * 128
  const int swz = (bid & 7) * 128 + (bid >> 3);
  const int m0 = (swz & 63) * 128;
  const int n0 = (swz >> 6) * 256;
  const int wm = (wv >> 1) * 64;
  const int wn = (wv & 1) * 128;

  const int r15 = lane & 15;
  const int kb = (lane >> 4) * 16;

  const char* pA = qh  + (long)(m0 + wm + r15) * 11008 + kb;
  const char* pB = qwd + (long)(n0 + wn + r15) * 11008 + kb;
  const long RS = 16L * 11008;

  int32x4 acc[4][8] = {};
  int32x4 a0[4], b0[8], a1[4], b1[8];

  #define DN_LOAD(ar, br, k0)                                  \
    do {                                                       \
      _Pragma("unroll")                                        \
      for (int m = 0; m < 4; m++)                              \
        ar[m] = *(const int32x4*)(pA + m * RS + (k0));         \
      _Pragma("unroll")                                        \
      for (int n = 0; n < 8; n++)                              \
        br[n] = *(const int32x4*)(pB + n * RS + (k0));         \
    } while (0)

  #define DN_MFMA(ar, br)                                                    \
    do {                                                                     \
      __builtin_amdgcn_s_setprio(1);                                         \
      _Pragma("unroll")                                                      \
      for (int n = 0; n < 8; n++) {                                          \
        _Pragma("unroll")                                                    \
        for (int m = 0; m < 4; m++)                                          \
          acc[m][n] = __builtin_amdgcn_mfma_i32_16x16x64_i8(ar[m], br[n], acc[m][n], 0, 0, 0); \
      }                                                                      \
      __builtin_amdgcn_s_setprio(0);                                         \
    } while (0)

  DN_LOAD(a0, b0, 0);
  for (int ks = 0; ks < 172; ks += 2) {
    if (ks + 1 < 172) DN_LOAD(a1, b1, (ks + 1) * 64);
    DN_MFMA(a0, b0);
    if (ks + 2 < 172) DN_LOAD(a0, b0, (ks + 2) * 64);
    DN_MFMA(a1, b1);
  }
  #undef DN_LOAD
  #undef DN_MFMA

  float fwd = fmaxf(meanw[2], 1e-5f);
  const int rgrp = lane >> 4;
  const int cidx = lane & 15;
  #pragma unroll
  for (int m = 0; m < 4; m++) {
    #pragma unroll
    for (int r = 0; r < 4; r++) {
      int grow = m0 + wm + m * 16 + rgrp * 4 + r;
      float f = fh[grow] * fwd;
      #pragma unroll
      for (int n = 0; n < 8; n++) {
        out[(long)grow * 4096 + (n0 + wn + n * 16 + cidx)] =
            (float)acc[m][n][r] * f;
      }
    }
  }
}

// ---------------------------------------------------------------- launch
extern "C" void kernel_launch(void* const* d_in, const int* in_sizes, int n_in,
                              void* d_out, int out_size, void* d_ws, size_t ws_size,
                              hipStream_t stream) {
  const float* x      = (const float*)d_in[0];
  const float* w_gate = (const float*)d_in[1];
  const float* w_up   = (const float*)d_in[2];
  const float* w_down = (const float*)d_in[3];
  float* out = (float*)d_out;

  const long NW = 11008L * 4096L;     // 45088768 per weight
  const long NX = 8192L * 4096L;      // 33554432
  const long NH = 8192L * 11008L;     // 90177536

  char* ws  = (char*)d_ws;
  char* qwg = ws;
  char* qwu = qwg + NW;
  char* qwd = qwu + NW;
  char* qx  = qwd + NW;
  char* qh  = qx + NX;
  float* h  = (float*)(qh + NH);
  float* fx = h + NH;                 // 8192 floats
  float* fh = fx + 8192;              // 8192 floats
  float* meanw = fh + 8192;           // [0]=gate [1]=up [2]=down (+pad)
  float* bs    = meanw + 4;           // 3*131072 floats
  float* part  = bs + 3 * 131072;     // 3*256 floats
  int*   ccnt  = (int*)(part + 1024);
  int*   ck    = ccnt + 4;            // CORR_MAX ints
  float* cv    = (float*)(ck + CORR_MAX);

  zero_cnt<<<1, 1, 0, stream>>>(ccnt);

  // numpy-style fp32 pairwise means, all three matrices fused per level
  np_blocksums3<<<1536, 256, 0, stream>>>(w_gate, w_up, w_down, bs);
  np_tree_partial3<<<768, 256, 0, stream>>>(bs, part);
  np_tree_final3<<<3, 128, 0, stream>>>(part, meanw);

  quant_w_gu<<<8192, 256, 0, stream>>>(w_gate, w_up, meanw, qwg, qwu, NW / 4);
  quant_w_down<<<4096, 256, 0, stream>>>(w_down, meanw, qwd, ccnt, ck, cv);

  act_quant_x<<<8192, 256, 0, stream>>>(x, qx, fx);

  gemm_gateup<<<5504, 256, 0, stream>>>(qx, qwg, qwu, meanw, fx, h);

  act_quant_h<<<8192, 256, 0, stream>>>(h, qh, fh);

  gemm_down<<<1024, 256, 0, stream>>>(qh, qwd, meanw, fh, out);

  apply_corr<<<128, 64, 0, stream>>>(ccnt, ck, cv, qh, fh, meanw, out);
}

// Round 13
// 1686.989 us; speedup vs baseline: 1.9652x; 1.9652x over previous
//
#include <hip/hip_runtime.h>
#include <hip/hip_bf16.h>
#include <cstdint>

#define EPS 1e-5

typedef __attribute__((ext_vector_type(4))) int int32x4;

// ---------------------------------------------------------------- async global->LDS
__device__ __forceinline__ void gload(const char* g, char* l) {
  __builtin_amdgcn_global_load_lds(
      (const __attribute__((address_space(1))) unsigned int*)g,
      (__attribute__((address_space(3))) unsigned int*)l, 16, 0, 0);
}

// =============================================================================
// numpy-exact fp32 pairwise mean of |w| (see round 2-4 notes).
// =============================================================================
__device__ inline float np_leaf_abs(const float* __restrict__ a, int n) {
  float r[8];
  #pragma unroll
  for (int j = 0; j < 8; j++) r[j] = fabsf(a[j]);
  for (int i = 8; i < n; i += 8) {
    #pragma unroll
    for (int j = 0; j < 8; j++) r[j] += fabsf(a[i + j]);
  }
  return ((r[0] + r[1]) + (r[2] + r[3])) + ((r[4] + r[5]) + (r[6] + r[7]));
}

__global__ __launch_bounds__(256) void np_blocksums3(
    const float* __restrict__ w0, const float* __restrict__ w1,
    const float* __restrict__ w2, float* __restrict__ bs) {
  int b = blockIdx.x * 256 + threadIdx.x;       // [0, 393216)
  const float* w = (b < 131072) ? w0 : (b < 262144 ? w1 : w2);
  long lb = b & 131071;
  const float* a = w + lb * 344;
  float s0 = np_leaf_abs(a, 80);
  float s1 = np_leaf_abs(a + 80, 88);
  float s2 = np_leaf_abs(a + 168, 88);
  float s3 = np_leaf_abs(a + 256, 88);
  bs[b] = (s0 + s1) + (s2 + s3);
}

__global__ __launch_bounds__(256) void np_tree_partial3(
    const float* __restrict__ bs, float* __restrict__ part) {
  __shared__ float sh[256];
  int t = threadIdx.x;
  const float* a = bs + (long)blockIdx.x * 512;   // grid 768 = 3*256
  sh[t] = a[2 * t] + a[2 * t + 1];
  __syncthreads();
  for (int n = 128; n >= 1; n >>= 1) {
    float x = 0.f;
    if (t < n) x = sh[2 * t] + sh[2 * t + 1];
    __syncthreads();
    if (t < n) sh[t] = x;
    __syncthreads();
  }
  if (t == 0) part[blockIdx.x] = sh[0];
}

__global__ __launch_bounds__(128) void np_tree_final3(
    const float* __restrict__ part, float* __restrict__ meanw) {
  __shared__ float sh[128];
  int t = threadIdx.x;
  const float* p = part + blockIdx.x * 256;     // grid 3
  sh[t] = p[2 * t] + p[2 * t + 1];
  __syncthreads();
  for (int n = 64; n >= 1; n >>= 1) {
    float x = 0.f;
    if (t < n) x = sh[2 * t] + sh[2 * t + 1];
    __syncthreads();
    if (t < n) sh[t] = x;
    __syncthreads();
  }
  if (t == 0) meanw[blockIdx.x] = sh[0] / 45088768.0f;
}

// ------------------------------------------------------- weight ternarize
__global__ __launch_bounds__(256) void quant_w_gu(
    const float* __restrict__ wg, const float* __restrict__ wu,
    const float* __restrict__ meanw, char* __restrict__ qg, char* __restrict__ qu,
    long n4) {
  int half = (blockIdx.x >= 4096);
  const float* w = half ? wu : wg;
  char* q = half ? qu : qg;
  float scale = 1.0f / fmaxf(meanw[half], 1e-5f);
  long i = (long)(blockIdx.x & 4095) * blockDim.x + threadIdx.x;
  long stride = 4096L * blockDim.x;
  const float4* w4 = (const float4*)w;
  char4* q4 = (char4*)q;
  for (; i < n4; i += stride) {
    float4 v = w4[i];
    char4 c;
    c.x = (char)(int)fminf(1.f, fmaxf(-1.f, rintf(v.x * scale)));
    c.y = (char)(int)fminf(1.f, fmaxf(-1.f, rintf(v.y * scale)));
    c.z = (char)(int)fminf(1.f, fmaxf(-1.f, rintf(v.z * scale)));
    c.w = (char)(int)fminf(1.f, fmaxf(-1.f, rintf(v.w * scale)));
    q4[i] = c;
  }
}

#define CORR_MAX 1024
#define WIN 1e-6f

__global__ __launch_bounds__(256) void quant_w_down(
    const float* __restrict__ w, const float* __restrict__ mean_ptr,
    char* __restrict__ q, int* __restrict__ cnt,
    int* __restrict__ ck, float* __restrict__ cv) {
  float scale = 1.0f / fmaxf(mean_ptr[2], 1e-5f);
  long i0 = ((long)blockIdx.x * blockDim.x + threadIdx.x) * 4;
  long stride = (long)gridDim.x * blockDim.x * 4;
  for (long i = i0; i < 4096L * 11008L; i += stride) {
    char4 c;
    #pragma unroll
    for (int j = 0; j < 4; j++) {
      float t = w[i + j] * scale;
      float qv = fminf(1.f, fmaxf(-1.f, rintf(t)));
      if (fabsf(fabsf(t) - 0.5f) < WIN) {
        qv = 0.f;
        int idx = atomicAdd(cnt, 1);
        if (idx < CORR_MAX) {
          ck[idx] = (int)(i + j);                 // flat n*11008+k
          cv[idx] = t > 0.f ? 0.5f : -0.5f;
        }
      }
      ((char*)&c)[j] = (char)(int)qv;
    }
    *(char4*)(q + i) = c;
  }
}

__global__ void zero_cnt(int* cnt) { *cnt = 0; }

__global__ __launch_bounds__(64) void apply_corr(
    const int* __restrict__ cnt, const int* __restrict__ ck,
    const float* __restrict__ cv, const char* __restrict__ qh,
    const float* __restrict__ fh, const float* __restrict__ meanw,
    float* __restrict__ out) {
  int r = blockIdx.x * 64 + threadIdx.x;  // 8192 rows
  float fwd = fmaxf(meanw[2], 1e-5f);
  int n = *cnt; if (n > CORR_MAX) n = CORR_MAX;
  float fr = fh[r] * fwd;
  for (int i = 0; i < n; i++) {
    int flat = ck[i];
    int nn = flat / 11008, kk = flat % 11008;
    float qv = (float)qh[(long)r * 11008 + kk];
    out[(long)r * 4096 + nn] += cv[i] * qv * fr;
  }
}

// ---------------------------------------------------------------- reductions
__device__ inline void block_reduce_sum_max_d(double& s, float& m) {
  #pragma unroll
  for (int off = 1; off < 64; off <<= 1) {
    s += __shfl_xor(s, off, 64);
    m = fmaxf(m, __shfl_xor(m, off, 64));
  }
  __shared__ double ssh[4];
  __shared__ float msh[4];
  int wv = threadIdx.x >> 6;
  if ((threadIdx.x & 63) == 0) { ssh[wv] = s; msh[wv] = m; }
  __syncthreads();
  s = (ssh[0] + ssh[1]) + (ssh[2] + ssh[3]);
  m = fmaxf(fmaxf(msh[0], msh[1]), fmaxf(msh[2], msh[3]));
}

// ------------------------------------------------------- activation quant
__device__ inline char quant1d(float x, double rn, double s) {
  double t = (double)x * rn;
  double q = rint(t * s);
  q = fmin(127.0, fmax(-128.0, q));
  return (char)(int)q;
}

__global__ __launch_bounds__(256) void act_quant_x(
    const float* __restrict__ x, char* __restrict__ qx, float* __restrict__ fx) {
  const int row = blockIdx.x;
  const float4* xr = (const float4*)(x + (long)row * 4096);
  float4 v[4];
  double ss = 0.0;
  float am = 0.f;
  #pragma unroll
  for (int i = 0; i < 4; i++) {
    v[i] = xr[i * 256 + threadIdx.x];
    ss += ((double)v[i].x * v[i].x + (double)v[i].y * v[i].y) +
          ((double)v[i].z * v[i].z + (double)v[i].w * v[i].w);
    am = fmaxf(am, fmaxf(fmaxf(fabsf(v[i].x), fabsf(v[i].y)),
                         fmaxf(fabsf(v[i].z), fabsf(v[i].w))));
  }
  block_reduce_sum_max_d(ss, am);
  double rn = 1.0 / sqrt(ss / 4096.0 + EPS);
  double den = fmax((double)am * rn, EPS);
  double s = 127.0 / den;
  if (threadIdx.x == 0) fx[row] = (float)(den / 127.0);
  char4* qr = (char4*)(qx + (long)row * 4096);
  #pragma unroll
  for (int i = 0; i < 4; i++) {
    char4 c;
    c.x = quant1d(v[i].x, rn, s);
    c.y = quant1d(v[i].y, rn, s);
    c.z = quant1d(v[i].z, rn, s);
    c.w = quant1d(v[i].w, rn, s);
    qr[i * 256 + threadIdx.x] = c;
  }
}

// h row cached in LDS (44KB) so the quant pass doesn't re-read 360MB from HBM.
__global__ __launch_bounds__(256) void act_quant_h(
    const float* __restrict__ h, char* __restrict__ qh, float* __restrict__ fh) {
  __shared__ float4 hrow4[2752];
  const long row = blockIdx.x;
  const float4* hr = (const float4*)(h + row * 11008);
  double ss = 0.0;
  float am = 0.f;
  for (int i = threadIdx.x; i < 2752; i += 256) {
    float4 v = hr[i];
    hrow4[i] = v;
    ss += ((double)v.x * v.x + (double)v.y * v.y) +
          ((double)v.z * v.z + (double)v.w * v.w);
    am = fmaxf(am, fmaxf(fmaxf(fabsf(v.x), fabsf(v.y)),
                         fmaxf(fabsf(v.z), fabsf(v.w))));
  }
  block_reduce_sum_max_d(ss, am);   // contains __syncthreads (covers hrow4)
  double rn = 1.0 / sqrt(ss / 11008.0 + EPS);
  double den = fmax((double)am * rn, EPS);
  double s = 127.0 / den;
  if (threadIdx.x == 0) fh[row] = (float)(den / 127.0);
  char4* qr = (char4*)(qh + row * 11008);
  for (int i = threadIdx.x; i < 2752; i += 256) {
    float4 v = hrow4[i];
    char4 c;
    c.x = quant1d(v.x, rn, s);
    c.y = quant1d(v.y, rn, s);
    c.z = quant1d(v.z, rn, s);
    c.w = quant1d(v.w, rn, s);
    qr[i] = c;
  }
}

// =============================================================================
// GEMMs, mfma_i32_16x16x64_i8, r9 conflict-free rotation swizzle (PMC 0).
// Occupancy-first restructure: 8 waves/block, 24KB/buffer x 3 buffers = 72KB
// -> 2 blocks/CU = 4 wave-contexts/SIMD (was 2 — the 43% plateau cause).
// Phase-split K-tiles (T3): gateup tile = {a,bg reads -> MFMA g -> barrier}
// then {bu reads -> MFMA u -> counted vmcnt -> barrier}; stage issues spread
// across phases. 3-buffer pointer rotation, stage distance 2, vmcnt(3)
// (= this tile's 3 loads stay in flight; never drains in steady state).
//   gateup: 128x128 tile, 8 waves (2m x 4n of 64x32 per matrix).
//   down:   128x256 tile, 8 waves (2m x 4n of 64x64), single phase.
// XCD-bijective swizzle, m-fastest (B panels L2-hot).
// =============================================================================

__global__ __launch_bounds__(512, 4) void gemm_gateup(
    const char* __restrict__ qx, const char* __restrict__ qwg, const char* __restrict__ qwu,
    const float* __restrict__ meanw, const float* __restrict__ fx, float* __restrict__ h) {
  __shared__ __align__(16) char As[3][8192];
  __shared__ __align__(16) char Bgs[3][8192];
  __shared__ __align__(16) char Bus[3][8192];
  const int t = threadIdx.x;
  const int lane = t & 63;
  const int wv = t >> 6;                       // 0..7
  const int bid = blockIdx.x;                  // 5504 = 8 * 688
  const int swz = (bid & 7) * 688 + (bid >> 3);
  const int m0 = (swz & 63) * 128;
  const int n0 = (swz >> 6) * 128;
  const int wm = (wv >> 2) * 64;               // 0,64
  const int wn = (wv & 3) * 32;                // 0..96

  const int gcol = (((lane & 3) - ((lane >> 3) & 3)) & 3) * 16;
  const int loff = (lane & 15) * 64 + ((((lane >> 4) + ((lane >> 1) & 3)) & 3) << 4);

  // 512 threads, 1 gload per matrix per tile: row = wv*16 + (lane>>2)
  const char* gA = qx  + (long)(m0 + wv * 16 + (lane >> 2)) * 4096 + gcol;
  const char* gG = qwg + (long)(n0 + wv * 16 + (lane >> 2)) * 4096 + gcol;
  const char* gU = qwu + (long)(n0 + wv * 16 + (lane >> 2)) * 4096 + gcol;

  int32x4 accg[4][2] = {};
  int32x4 accu[4][2] = {};

  char *PA0 = &As[0][0], *PA1 = &As[1][0], *PA2 = &As[2][0];
  char *PG0 = &Bgs[0][0], *PG1 = &Bgs[1][0], *PG2 = &Bgs[2][0];
  char *PU0 = &Bus[0][0], *PU1 = &Bus[1][0], *PU2 = &Bus[2][0];

  // prologue: stage tiles 0,1
  gload(gA, PA0 + wv * 1024);
  gload(gG, PG0 + wv * 1024);
  gload(gU, PU0 + wv * 1024);
  gload(gA + 64, PA1 + wv * 1024);
  gload(gG + 64, PG1 + wv * 1024);
  gload(gU + 64, PU1 + wv * 1024);
  asm volatile("s_waitcnt vmcnt(3)" ::: "memory");   // tile 0 landed
  __builtin_amdgcn_s_barrier();

  for (int ks = 0; ks < 64; ++ks) {
    int32x4 a[4], bg[2], bu[2];
    // ----- phase A: a + bg reads, stage A/G for tile ks+2, MFMA gate
    #pragma unroll
    for (int m = 0; m < 4; m++)
      a[m] = *(const int32x4*)(PA0 + (wm + m * 16) * 64 + loff);
    #pragma unroll
    for (int n = 0; n < 2; n++)
      bg[n] = *(const int32x4*)(PG0 + (wn + n * 16) * 64 + loff);
    if (ks + 2 < 64) {
      gload(gA + (ks + 2) * 64, PA2 + wv * 1024);
      gload(gG + (ks + 2) * 64, PG2 + wv * 1024);
    }
    __builtin_amdgcn_s_setprio(1);
    #pragma unroll
    for (int n = 0; n < 2; n++) {
      #pragma unroll
      for (int m = 0; m < 4; m++)
        accg[m][n] = __builtin_amdgcn_mfma_i32_16x16x64_i8(a[m], bg[n], accg[m][n], 0, 0, 0);
    }
    __builtin_amdgcn_s_setprio(0);
    __builtin_amdgcn_s_barrier();
    // ----- phase B: bu reads, stage U, MFMA up, counted vmcnt
    #pragma unroll
    for (int n = 0; n < 2; n++)
      bu[n] = *(const int32x4*)(PU0 + (wn + n * 16) * 64 + loff);
    if (ks + 2 < 64) gload(gU + (ks + 2) * 64, PU2 + wv * 1024);
    __builtin_amdgcn_s_setprio(1);
    #pragma unroll
    for (int n = 0; n < 2; n++) {
      #pragma unroll
      for (int m = 0; m < 4; m++)
        accu[m][n] = __builtin_amdgcn_mfma_i32_16x16x64_i8(a[m], bu[n], accu[m][n], 0, 0, 0);
    }
    __builtin_amdgcn_s_setprio(0);
    if (ks < 62) asm volatile("s_waitcnt vmcnt(3)" ::: "memory");
    else         asm volatile("s_waitcnt vmcnt(0)" ::: "memory");
    __builtin_amdgcn_s_barrier();
    char* tp;
    tp = PA0; PA0 = PA1; PA1 = PA2; PA2 = tp;
    tp = PG0; PG0 = PG1; PG1 = PG2; PG2 = tp;
    tp = PU0; PU0 = PU1; PU1 = PU2; PU2 = tp;
  }

  float fwg = fmaxf(meanw[0], 1e-5f);
  float fwu = fmaxf(meanw[1], 1e-5f);
  const int rgrp = lane >> 4;
  const int cidx = lane & 15;
  #pragma unroll
  for (int m = 0; m < 4; m++) {
    #pragma unroll
    for (int r = 0; r < 4; r++) {
      int grow = m0 + wm + m * 16 + rgrp * 4 + r;
      float fxr = fx[grow];
      float sg = fxr * fwg, su = fxr * fwu;
      #pragma unroll
      for (int n = 0; n < 2; n++) {
        float g = (float)accg[m][n][r] * sg;
        float u = (float)accu[m][n][r] * su;
        float hv = g / (1.f + expf(-g)) * u;
        h[(long)grow * 11008 + (n0 + wn + n * 16 + cidx)] = hv;
      }
    }
  }
}

__global__ __launch_bounds__(512, 4) void gemm_down(
    const char* __restrict__ qh, const char* __restrict__ qwd,
    const float* __restrict__ meanw, const float* __restrict__ fh,
    float* __restrict__ out) {
  __shared__ __align__(16) char As[3][8192];
  __shared__ __align__(16) char Bs[3][16384];
  const int t = threadIdx.x;
  const int lane = t & 63;
  const int wv = t >> 6;
  const int bid = blockIdx.x;                  // 1024 = 8 * 128
  const int swz = (bid & 7) * 128 + (bid >> 3);
  const int m0 = (swz & 63) * 128;
  const int n0 = (swz >> 6) * 256;
  const int wm = (wv >> 2) * 64;
  const int wn = (wv & 3) * 64;

  const int gcol = (((lane & 3) - ((lane >> 3) & 3)) & 3) * 16;
  const int loff = (lane & 15) * 64 + ((((lane >> 4) + ((lane >> 1) & 3)) & 3) << 4);

  const char* gA  = qh  + (long)(m0 + wv * 16 + (lane >> 2)) * 11008 + gcol;
  const char* gB  = qwd + (long)(n0 + wv * 16 + (lane >> 2)) * 11008 + gcol;
  const char* gB2 = gB + 128L * 11008;

  int32x4 acc[4][4] = {};

  char *PA0 = &As[0][0], *PA1 = &As[1][0], *PA2 = &As[2][0];
  char *PB0 = &Bs[0][0], *PB1 = &Bs[1][0], *PB2 = &Bs[2][0];

  gload(gA, PA0 + wv * 1024);
  gload(gB, PB0 + wv * 1024);
  gload(gB2, PB0 + 8192 + wv * 1024);
  gload(gA + 64, PA1 + wv * 1024);
  gload(gB + 64, PB1 + wv * 1024);
  gload(gB2 + 64, PB1 + 8192 + wv * 1024);
  asm volatile("s_waitcnt vmcnt(3)" ::: "memory");
  __builtin_amdgcn_s_barrier();

  for (int ks = 0; ks < 172; ++ks) {
    int32x4 a[4], b[4];
    #pragma unroll
    for (int m = 0; m < 4; m++)
      a[m] = *(const int32x4*)(PA0 + (wm + m * 16) * 64 + loff);
    #pragma unroll
    for (int n = 0; n < 4; n++)
      b[n] = *(const int32x4*)(PB0 + (wn + n * 16) * 64 + loff);
    if (ks + 2 < 172) {
      gload(gA + (ks + 2) * 64, PA2 + wv * 1024);
      gload(gB + (ks + 2) * 64, PB2 + wv * 1024);
      gload(gB2 + (ks + 2) * 64, PB2 + 8192 + wv * 1024);
    }
    __builtin_amdgcn_s_setprio(1);
    #pragma unroll
    for (int n = 0; n < 4; n++) {
      #pragma unroll
      for (int m = 0; m < 4; m++)
        acc[m][n] = __builtin_amdgcn_mfma_i32_16x16x64_i8(a[m], b[n], acc[m][n], 0, 0, 0);
    }
    __builtin_amdgcn_s_setprio(0);
    if (ks < 170) asm volatile("s_waitcnt vmcnt(3)" ::: "memory");
    else          asm volatile("s_waitcnt vmcnt(0)" ::: "memory");
    __builtin_amdgcn_s_barrier();
    char* tp;
    tp = PA0; PA0 = PA1; PA1 = PA2; PA2 = tp;
    tp = PB0; PB0 = PB1; PB1 = PB2; PB2 = tp;
  }

  float fwd = fmaxf(meanw[2], 1e-5f);
  const int rgrp = lane >> 4;
  const int cidx = lane & 15;
  #pragma unroll
  for (int m = 0; m < 4; m++) {
    #pragma unroll
    for (int r = 0; r < 4; r++) {
      int grow = m0 + wm + m * 16 + rgrp * 4 + r;
      float f = fh[grow] * fwd;
      #pragma unroll
      for (int n = 0; n < 4; n++) {
        out[(long)grow * 4096 + (n0 + wn + n * 16 + cidx)] =
            (float)acc[m][n][r] * f;
      }
    }
  }
}

// ---------------------------------------------------------------- launch
extern "C" void kernel_launch(void* const* d_in, const int* in_sizes, int n_in,
                              void* d_out, int out_size, void* d_ws, size_t ws_size,
                              hipStream_t stream) {
  const float* x      = (const float*)d_in[0];
  const float* w_gate = (const float*)d_in[1];
  const float* w_up   = (const float*)d_in[2];
  const float* w_down = (const float*)d_in[3];
  float* out = (float*)d_out;

  const long NW = 11008L * 4096L;     // 45088768 per weight
  const long NX = 8192L * 4096L;      // 33554432
  const long NH = 8192L * 11008L;     // 90177536

  char* ws  = (char*)d_ws;
  char* qwg = ws;
  char* qwu = qwg + NW;
  char* qwd = qwu + NW;
  char* qx  = qwd + NW;
  char* qh  = qx + NX;
  float* h  = (float*)(qh + NH);
  float* fx = h + NH;                 // 8192 floats
  float* fh = fx + 8192;              // 8192 floats
  float* meanw = fh + 8192;           // [0]=gate [1]=up [2]=down (+pad)
  float* bs    = meanw + 4;           // 3*131072 floats
  float* part  = bs + 3 * 131072;     // 3*256 floats
  int*   ccnt  = (int*)(part + 1024);
  int*   ck    = ccnt + 4;            // CORR_MAX ints
  float* cv    = (float*)(ck + CORR_MAX);

  zero_cnt<<<1, 1, 0, stream>>>(ccnt);

  // numpy-style fp32 pairwise means, all three matrices fused per level
  np_blocksums3<<<1536, 256, 0, stream>>>(w_gate, w_up, w_down, bs);
  np_tree_partial3<<<768, 256, 0, stream>>>(bs, part);
  np_tree_final3<<<3, 128, 0, stream>>>(part, meanw);

  quant_w_gu<<<8192, 256, 0, stream>>>(w_gate, w_up, meanw, qwg, qwu, NW / 4);
  quant_w_down<<<4096, 256, 0, stream>>>(w_down, meanw, qwd, ccnt, ck, cv);

  act_quant_x<<<8192, 256, 0, stream>>>(x, qx, fx);

  gemm_gateup<<<5504, 512, 0, stream>>>(qx, qwg, qwu, meanw, fx, h);

  act_quant_h<<<8192, 256, 0, stream>>>(h, qh, fh);

  gemm_down<<<1024, 512, 0, stream>>>(qh, qwd, meanw, fh, out);

  apply_corr<<<128, 64, 0, stream>>>(ccnt, ck, cv, qh, fh, meanw, out);
}